// Round 9
// baseline (309.305 us; speedup 1.0000x reference)
//
#include <hip/hip_runtime.h>

#define NN 50000
#define EE 800000
#define DIM 128
#define KK 256          // concat K: [agg(128) | self(128)]
#define OUTD 4
#define EPSV 1e-5f
#define OTS 132         // oT row stride (floats)

using short8v = __attribute__((ext_vector_type(8))) short;   // 8 bf16
using f32x4v  = __attribute__((ext_vector_type(4))) float;

__device__ __forceinline__ unsigned short f2bf(float f) {
    union { float f; unsigned u; } x; x.f = f;
    unsigned r = x.u + 0x7FFF + ((x.u >> 16) & 1);   // RNE
    return (unsigned short)(r >> 16);
}
__device__ __forceinline__ float bf2f(unsigned short u) {
    union { unsigned u; float f; } x; x.u = ((unsigned)u) << 16;
    return x.f;
}

// ---------------------------------------------------------------------------
// prep: role-split grid.
//   blocks [0, 6250):        x f32 -> xb bf16 (1 float4/thread, exact)
//   blocks [6250, 6506):     Wt bf16 [128 j][256 k] for both layers
//   blocks [6506, 9631):     dst histogram (cnt pre-zeroed by memset)
// ---------------------------------------------------------------------------
#define XB_BLK 6250
#define W_BLK  256
#define H_BLK  3125
__global__ __launch_bounds__(256) void prep_kernel(
    const float* __restrict__ x, ushort* __restrict__ xb,
    const float* __restrict__ Wl0, const float* __restrict__ Wr0,
    const float* __restrict__ Wl1, const float* __restrict__ Wr1,
    ushort* __restrict__ Wt0, ushort* __restrict__ Wt1,
    const int* __restrict__ dst, int* __restrict__ cnt)
{
    int b = blockIdx.x;
    if (b < XB_BLK) {
        int i = b * 256 + threadIdx.x;             // < 1,600,000 exactly
        float4 v = ((const float4*)x)[i];
        ushort4 o;
        o.x = f2bf(v.x); o.y = f2bf(v.y); o.z = f2bf(v.z); o.w = f2bf(v.w);
        ((ushort4*)xb)[i] = o;
    } else if (b < XB_BLK + W_BLK) {
        int idx = (b - XB_BLK) * 256 + threadIdx.x;   // 0..65535
        int which = idx >> 15;
        int j = (idx >> 8) & 127;
        int k = idx & 255;
        const float* Wl = which ? Wl1 : Wl0;
        const float* Wr = which ? Wr1 : Wr0;
        ushort* Wt = which ? Wt1 : Wt0;
        float v = (k < 128) ? Wl[k * DIM + j] : Wr[(k - 128) * DIM + j];
        Wt[j * KK + k] = f2bf(v);
    } else {
        int e = (b - XB_BLK - W_BLK) * 256 + threadIdx.x;
        if (e < EE) atomicAdd(&cnt[dst[e]], 1);
    }
}

// ---------------------------------------------------------------------------
// Register-blocked exclusive scan, one block of 1024 threads.
// Thread t owns ints [t*52, t*52+52) (13 int4). One block-scan round.
// Writes rowptr[0..NN] and cursor[0..NN) = rowptr (fill bumps cursor).
// ---------------------------------------------------------------------------
__global__ __launch_bounds__(1024) void scan_kernel(
    const int* __restrict__ cnt, int* __restrict__ rowptr,
    int* __restrict__ cursor)
{
    __shared__ int wsum[16];
    int tid = threadIdx.x, lane = tid & 63, wid = tid >> 6;
    int4 q[13];
    #pragma unroll
    for (int j = 0; j < 13; j++) {
        int qi = tid * 13 + j;
        int4 v = make_int4(0, 0, 0, 0);
        if (qi < NN / 4) v = ((const int4*)cnt)[qi];
        q[j] = v;
    }
    int run = 0;
    #pragma unroll
    for (int j = 0; j < 13; j++) {
        int a;
        a = q[j].x; q[j].x = run; run += a;
        a = q[j].y; q[j].y = run; run += a;
        a = q[j].z; q[j].z = run; run += a;
        a = q[j].w; q[j].w = run; run += a;
    }
    int tot = run;
    int s = tot;
    #pragma unroll
    for (int off = 1; off < 64; off <<= 1) {
        int u = __shfl_up(s, off, 64);
        if (lane >= off) s += u;
    }
    if (lane == 63) wsum[wid] = s;
    __syncthreads();
    if (tid < 16) {
        int wv = wsum[tid];
        #pragma unroll
        for (int off = 1; off < 16; off <<= 1) {
            int u = __shfl_up(wv, off, 16);
            if (tid >= off) wv += u;
        }
        wsum[tid] = wv;
    }
    __syncthreads();
    int excl = (wid ? wsum[wid - 1] : 0) + (s - tot);

    #pragma unroll
    for (int j = 0; j < 13; j++) {
        int qi = tid * 13 + j;
        int bi = qi * 4;
        int4 o = make_int4(q[j].x + excl, q[j].y + excl, q[j].z + excl, q[j].w + excl);
        if (bi + 3 < NN) {
            ((int4*)rowptr)[qi] = o;
            ((int4*)cursor)[qi] = o;
        } else if (bi <= NN) {
            int vv[4] = { o.x, o.y, o.z, o.w };
            #pragma unroll
            for (int c = 0; c < 4; c++) {
                int idx = bi + c;
                if (idx < NN) { rowptr[idx] = vv[c]; cursor[idx] = vv[c]; }
                else if (idx == NN) rowptr[idx] = vv[c];
            }
        }
    }
}

// ---------------------------------------------------------------------------
// fill: cursor pre-initialized to rowptr -> atomicAdd returns absolute slot.
// Non-temporal col store: scattered 4B writes shouldn't occupy cache lines.
// ---------------------------------------------------------------------------
__global__ __launch_bounds__(256) void fill_kernel(
    const int* __restrict__ src, const int* __restrict__ dst,
    int* __restrict__ cursor, int* __restrict__ col)
{
    int e = blockIdx.x * 256 + threadIdx.x;
    if (e >= EE) return;
    int d = __builtin_nontemporal_load(&dst[e]);
    int v = __builtin_nontemporal_load(&src[e]);
    int pos = atomicAdd(&cursor[d], 1);
    __builtin_nontemporal_store(v, &col[pos]);
}

// ---------------------------------------------------------------------------
// Fused layer. Gather (transposed ownership): thread t owns node t>>3 and
// feature slice [(t&7)*16, +16) (16 f32 accumulators). All 32 nodes of the
// block proceed in parallel; 4-edge rounds (8x16B loads in flight/thread).
// featB row layout (bytes): agg = [0,256), self = [256,512), both XOR-
// swizzled by ((n&7)<<4) on bits 4..6.
// ---------------------------------------------------------------------------
template <int DO_HEAD>
__global__ __launch_bounds__(256) void sage_fused_kernel(
    const ushort* __restrict__ featG,     // bf16 [N][128]
    const int* __restrict__ rowptr, const int* __restrict__ col,
    const ushort* __restrict__ WtB,       // bf16 [128 j][256 k]
    const float* __restrict__ bl,
    const float* __restrict__ g, const float* __restrict__ beta,
    const float* __restrict__ Wh, const float* __restrict__ bh,
    void* __restrict__ outp)
{
    __shared__ __align__(16) char smem[32 * OTS * 4];   // 16.9 KB
    __shared__ float mu_s[32], ri_s[32];
    ushort* featB = (ushort*)smem;            // [32][256] bf16, swizzled (16B granule)
    float*  oT    = (float*)smem;             // overlays featB after MFMA
    #define OT(n, k) oT[(n) * OTS + (k)]

    int tid = threadIdx.x;
    int base = blockIdx.x * 32;
    int lane = tid & 63, w = tid >> 6;

    // ---- self-feature part: featB bytes [256,512), ushort8 ----
    #pragma unroll
    for (int i = 0; i < 2; i++) {
        int idx = tid + i * 256;
        int n = idx >> 4, c = idx & 15;
        int node = base + n;
        short8v xv = {};
        if (node < NN) xv = *(const short8v*)(featG + (size_t)node * DIM + c * 8);
        int kb = (256 + c * 16) ^ ((n & 7) << 4);   // byte offset
        *(short8v*)(featB + n * KK + (kb >> 1)) = xv;
    }

    // ---- gather-mean: featB bytes [0,256), transposed ownership ----
    {
        int n = tid >> 3;          // 0..31: this thread's node
        int s8 = tid & 7;          // slice: elems [s8*16, s8*16+16)
        int node = base + n;
        int beg = 0, end = 0;
        if (node < NN) { beg = rowptr[node]; end = rowptr[node + 1]; }
        int deg = end - beg;
        float a[16];
        #pragma unroll
        for (int j = 0; j < 16; j++) a[j] = 0.f;
        const ushort* fbase = featG + s8 * 16;
        int e = beg;
        for (; e + 3 < end; e += 4) {
            int s0 = col[e], s1 = col[e + 1], s2 = col[e + 2], s3 = col[e + 3];
            short8v v00 = *(const short8v*)(fbase + (size_t)s0 * DIM);
            short8v v01 = *(const short8v*)(fbase + (size_t)s0 * DIM + 8);
            short8v v10 = *(const short8v*)(fbase + (size_t)s1 * DIM);
            short8v v11 = *(const short8v*)(fbase + (size_t)s1 * DIM + 8);
            short8v v20 = *(const short8v*)(fbase + (size_t)s2 * DIM);
            short8v v21 = *(const short8v*)(fbase + (size_t)s2 * DIM + 8);
            short8v v30 = *(const short8v*)(fbase + (size_t)s3 * DIM);
            short8v v31 = *(const short8v*)(fbase + (size_t)s3 * DIM + 8);
            #pragma unroll
            for (int j = 0; j < 8; j++) {
                a[j]     += (bf2f((unsigned short)v00[j]) + bf2f((unsigned short)v10[j]))
                          + (bf2f((unsigned short)v20[j]) + bf2f((unsigned short)v30[j]));
                a[j + 8] += (bf2f((unsigned short)v01[j]) + bf2f((unsigned short)v11[j]))
                          + (bf2f((unsigned short)v21[j]) + bf2f((unsigned short)v31[j]));
            }
        }
        for (; e < end; e++) {
            int s0 = col[e];
            short8v v00 = *(const short8v*)(fbase + (size_t)s0 * DIM);
            short8v v01 = *(const short8v*)(fbase + (size_t)s0 * DIM + 8);
            #pragma unroll
            for (int j = 0; j < 8; j++) {
                a[j]     += bf2f((unsigned short)v00[j]);
                a[j + 8] += bf2f((unsigned short)v01[j]);
            }
        }
        float di = 1.0f / fmaxf((float)deg, 1.0f);
        short8v o0, o1;
        #pragma unroll
        for (int j = 0; j < 8; j++) {
            o0[j] = (short)f2bf(a[j] * di);
            o1[j] = (short)f2bf(a[j + 8] * di);
        }
        int kb0 = (s8 * 32) ^ ((n & 7) << 4);        // byte offsets, 16B chunks
        int kb1 = (s8 * 32 + 16) ^ ((n & 7) << 4);
        *(short8v*)(featB + n * KK + (kb0 >> 1)) = o0;
        *(short8v*)(featB + n * KK + (kb1 >> 1)) = o1;
    }
    __syncthreads();

    // ---- MFMA: C[32][128] = featB[32][256] x W[256][128] ----
    int l15 = lane & 15, q = lane >> 4;
    f32x4v acc00 = {}, acc01 = {}, acc10 = {}, acc11 = {};
    const ushort* wbase = WtB + (size_t)(w * 32) * KK;
    int n0 = l15, n1 = 16 + l15;
    int sw = (l15 & 7) << 4;
    #pragma unroll
    for (int ks = 0; ks < 8; ks++) {
        int kbA = ks * 64 + q * 16;                  // byte offset
        short8v a0 = *(const short8v*)(featB + n0 * KK + (((kbA) ^ sw) >> 1));
        short8v a1 = *(const short8v*)(featB + n1 * KK + (((kbA) ^ sw) >> 1));
        int koff = ks * 32 + q * 8;
        short8v b0 = *(const short8v*)(wbase + (size_t)l15 * KK + koff);
        short8v b1 = *(const short8v*)(wbase + (size_t)(16 + l15) * KK + koff);
        acc00 = __builtin_amdgcn_mfma_f32_16x16x32_bf16(a0, b0, acc00, 0, 0, 0);
        acc01 = __builtin_amdgcn_mfma_f32_16x16x32_bf16(a0, b1, acc01, 0, 0, 0);
        acc10 = __builtin_amdgcn_mfma_f32_16x16x32_bf16(a1, b0, acc10, 0, 0, 0);
        acc11 = __builtin_amdgcn_mfma_f32_16x16x32_bf16(a1, b1, acc11, 0, 0, 0);
    }
    __syncthreads();   // all featB reads done before oT overlays it

    // D layout: col = lane&15, row = (lane>>4)*4 + r
    {
        int c0 = w * 32 + l15, c1 = c0 + 16;
        float bl0v = bl[c0], bl1v = bl[c1];
        #pragma unroll
        for (int r = 0; r < 4; r++) {
            int r0 = q * 4 + r, r1 = 16 + q * 4 + r;
            OT(r0, c0) = acc00[r] + bl0v;
            OT(r0, c1) = acc01[r] + bl1v;
            OT(r1, c0) = acc10[r] + bl0v;
            OT(r1, c1) = acc11[r] + bl1v;
        }
    }
    __syncthreads();

    // ---- LayerNorm stats (f32): 8 threads per node ----
    {
        int n = tid >> 3, l = tid & 7;
        float s = 0.f, s2 = 0.f;
        #pragma unroll
        for (int kk = 0; kk < 16; kk++) {
            float v = OT(n, l * 16 + kk);
            s += v; s2 += v * v;
        }
        #pragma unroll
        for (int off = 4; off; off >>= 1) {
            s  += __shfl_down(s, off, 8);
            s2 += __shfl_down(s2, off, 8);
        }
        if (l == 0) {
            float mu = s * (1.0f / DIM);
            float var = s2 * (1.0f / DIM) - mu * mu;
            mu_s[n] = mu;
            ri_s[n] = rsqrtf(fmaxf(var, 0.f) + EPSV);
        }
    }
    __syncthreads();

    if (!DO_HEAD) {
        ushort* hout = (ushort*)outp;
        #pragma unroll
        for (int i = 0; i < 16; i++) {
            int idx = tid + i * 256;
            int n = idx >> 7, k = idx & 127;
            int node = base + n;
            if (node < NN) {
                float v = (OT(n, k) - mu_s[n]) * ri_s[n] * g[k] + beta[k];
                hout[(size_t)node * DIM + k] = f2bf(fmaxf(v, 0.f));
            }
        }
    } else {
        float* fout = (float*)outp;
        float vals[16];
        #pragma unroll
        for (int i = 0; i < 16; i++) {
            int idx = tid + i * 256;
            int n = idx >> 7, k = idx & 127;
            float v = (OT(n, k) - mu_s[n]) * ri_s[n] * g[k] + beta[k];
            vals[i] = fmaxf(v, 0.f);
        }
        __syncthreads();
        #pragma unroll
        for (int i = 0; i < 16; i++) {
            int idx = tid + i * 256;
            int n = idx >> 7, k = idx & 127;
            OT(n, k) = vals[i];
        }
        __syncthreads();
        if (tid < 128) {
            int n = tid >> 2, o = tid & 3;
            int node = base + n;
            if (node < NN) {
                float s = bh[o];
                for (int k = 0; k < DIM; k++) s += OT(n, k) * Wh[k * OUTD + o];
                fout[(size_t)node * OUTD + o] = s;
            }
        }
    }
    #undef OT
}

extern "C" void kernel_launch(void* const* d_in, const int* in_sizes, int n_in,
                              void* d_out, int out_size, void* d_ws, size_t ws_size,
                              hipStream_t stream)
{
    const float* x    = (const float*)d_in[0];
    const int*   ei   = (const int*)d_in[1];   // [2, E] int32
    const float* Wl0  = (const float*)d_in[2];
    const float* bl0  = (const float*)d_in[3];
    const float* Wr0  = (const float*)d_in[4];
    const float* Wl1  = (const float*)d_in[5];
    const float* bl1  = (const float*)d_in[6];
    const float* Wr1  = (const float*)d_in[7];
    const float* g0   = (const float*)d_in[8];
    const float* be0  = (const float*)d_in[9];
    const float* g1   = (const float*)d_in[10];
    const float* be1  = (const float*)d_in[11];
    const float* Wh   = (const float*)d_in[12];
    const float* bh   = (const float*)d_in[13];
    float* out = (float*)d_out;

    const int* srcI = ei;
    const int* dstI = ei + EE;

    // ws layout (16B-aligned): xb | h | Wt0 | Wt1 | rowptr | cnt | cursor | col
    char* p = (char*)d_ws;
    ushort* xb     = (ushort*)p;  p += (size_t)NN * DIM * 2;   // 12.8 MB
    ushort* h      = (ushort*)p;  p += (size_t)NN * DIM * 2;   // 12.8 MB
    ushort* Wt0    = (ushort*)p;  p += DIM * KK * 2;           // 64 KB
    ushort* Wt1    = (ushort*)p;  p += DIM * KK * 2;           // 64 KB
    int*    rowptr = (int*)p;     p += 50016 * 4;              // N+1, padded
    int*    cnt    = (int*)p;     p += NN * 4;
    int*    cursor = (int*)p;     p += NN * 4;
    int*    col    = (int*)p;

    hipMemsetAsync(cnt, 0, NN * sizeof(int), stream);
    prep_kernel<<<XB_BLK + W_BLK + H_BLK, 256, 0, stream>>>(
        x, xb, Wl0, Wr0, Wl1, Wr1, Wt0, Wt1, dstI, cnt);
    scan_kernel<<<1, 1024, 0, stream>>>(cnt, rowptr, cursor);
    fill_kernel<<<(EE + 255) / 256, 256, 0, stream>>>(srcI, dstI, cursor, col);

    const int blocks = (NN + 31) / 32;
    sage_fused_kernel<0><<<blocks, 256, 0, stream>>>(
        xb, rowptr, col, Wt0, bl0, g0, be0, nullptr, nullptr, (void*)h);
    sage_fused_kernel<1><<<blocks, 256, 0, stream>>>(
        h, rowptr, col, Wt1, bl1, g1, be1, Wh, bh, (void*)out);
}

// Round 10
// 212.676 us; speedup vs baseline: 1.4543x; 1.4543x over previous
//
#include <hip/hip_runtime.h>

#define NN 50000
#define EE 800000
#define DIM 128
#define KK 256          // concat K: [agg(128) | self(128)]
#define OUTD 4
#define EPSV 1e-5f
#define OTS 132         // oT row stride (floats)
#define NB 196          // buckets = dst >> 8
#define SLOT 8192       // fixed pairs slots per bucket (mean 4082, sd 64)
#define ACHUNK 4096     // edges per passA block
#define NA 196          // ceil(EE / ACHUNK)

using short8v = __attribute__((ext_vector_type(8))) short;   // 8 bf16
using f32x4v  = __attribute__((ext_vector_type(4))) float;

__device__ __forceinline__ unsigned short f2bf(float f) {
    union { float f; unsigned u; } x; x.f = f;
    unsigned r = x.u + 0x7FFF + ((x.u >> 16) & 1);   // RNE
    return (unsigned short)(r >> 16);
}
__device__ __forceinline__ float bf2f(unsigned short u) {
    union { unsigned u; float f; } x; x.u = ((unsigned)u) << 16;
    return x.f;
}

// ---------------------------------------------------------------------------
// prep: role-split grid.
//   blocks [0, 6250):        x f32 -> xb bf16
//   blocks [6250, 6506):     Wt bf16 [128 j][256 k] both layers
//   block  6506:             zero bucketCursor[NB]
// ---------------------------------------------------------------------------
#define XB_BLK 6250
#define W_BLK  256
__global__ __launch_bounds__(256) void prep_kernel(
    const float* __restrict__ x, ushort* __restrict__ xb,
    const float* __restrict__ Wl0, const float* __restrict__ Wr0,
    const float* __restrict__ Wl1, const float* __restrict__ Wr1,
    ushort* __restrict__ Wt0, ushort* __restrict__ Wt1,
    int* __restrict__ bucketCursor)
{
    int b = blockIdx.x;
    if (b < XB_BLK) {
        int i = b * 256 + threadIdx.x;             // < 1,600,000 exactly
        float4 v = ((const float4*)x)[i];
        ushort4 o;
        o.x = f2bf(v.x); o.y = f2bf(v.y); o.z = f2bf(v.z); o.w = f2bf(v.w);
        ((ushort4*)xb)[i] = o;
    } else if (b < XB_BLK + W_BLK) {
        int idx = (b - XB_BLK) * 256 + threadIdx.x;   // 0..65535
        int which = idx >> 15;
        int j = (idx >> 8) & 127;
        int k = idx & 255;
        const float* Wl = which ? Wl1 : Wl0;
        const float* Wr = which ? Wr1 : Wr0;
        ushort* Wt = which ? Wt1 : Wt0;
        float v = (k < 128) ? Wl[k * DIM + j] : Wr[(k - 128) * DIM + j];
        Wt[j * KK + k] = f2bf(v);
    } else {
        if (threadIdx.x < NB) bucketCursor[threadIdx.x] = 0;
    }
}

// ---------------------------------------------------------------------------
// passA: bucket-scatter edges into fixed bucket regions (coalesced writes).
// pairs[b*SLOT + i] = (dst << 16) | src  (both < 2^16).
// ---------------------------------------------------------------------------
__global__ __launch_bounds__(256) void passA_kernel(
    const int* __restrict__ src, const int* __restrict__ dst,
    int* __restrict__ bucketCursor, unsigned* __restrict__ pairs)
{
    __shared__ int hist[256];
    __shared__ int scanb[256];
    __shared__ int exStart[256];
    __shared__ int cur2[256];
    __shared__ int gBase[256];
    __shared__ unsigned stage[ACHUNK];
    int tid = threadIdx.x;
    int eBase = blockIdx.x * ACHUNK;
    int total = min(ACHUNK, EE - eBase);

    hist[tid] = 0;
    __syncthreads();

    // count
    #pragma unroll
    for (int i = 0; i < 16; i++) {
        int idx = i * 256 + tid;
        if (idx < total) {
            int d = dst[eBase + idx];
            atomicAdd(&hist[d >> 8], 1);
        }
    }
    __syncthreads();
    int cntv = hist[tid];
    scanb[tid] = cntv;
    __syncthreads();
    #pragma unroll
    for (int off = 1; off < 256; off <<= 1) {
        int add = (tid >= off) ? scanb[tid - off] : 0;
        __syncthreads();
        scanb[tid] += add;
        __syncthreads();
    }
    int ex = scanb[tid] - cntv;
    exStart[tid] = ex;
    cur2[tid] = ex;
    if (tid < NB) gBase[tid] = (cntv > 0) ? atomicAdd(&bucketCursor[tid], cntv) : 0;
    __syncthreads();

    // stage in bucket order
    #pragma unroll
    for (int i = 0; i < 16; i++) {
        int idx = i * 256 + tid;
        if (idx < total) {
            int e = eBase + idx;
            int d = dst[e], s = src[e];
            int bb = d >> 8;
            int sp = atomicAdd(&cur2[bb], 1);
            stage[sp] = ((unsigned)d << 16) | (unsigned)s;
        }
    }
    __syncthreads();

    // write out: contiguous per-bucket segments
    #pragma unroll
    for (int i = 0; i < 16; i++) {
        int idx = i * 256 + tid;
        if (idx < total) {
            unsigned v = stage[idx];
            int bb = v >> 24;
            int pos = gBase[bb] + (idx - exStart[bb]);
            if (pos < SLOT) pairs[(size_t)bb * SLOT + pos] = v;
        }
    }
}

// ---------------------------------------------------------------------------
// passB: one block per bucket. Per-dst count + LDS scan -> writes rowptr
// slice AND scatters col (ushort src) within the bucket's L2-local region.
// ---------------------------------------------------------------------------
__global__ __launch_bounds__(256) void passB_kernel(
    const int* __restrict__ bucketCursor,
    const unsigned* __restrict__ pairs,
    int* __restrict__ rowptr, ushort* __restrict__ colS)
{
    __shared__ int bscan[256];
    __shared__ int cw[256];
    __shared__ int pre2[256];
    __shared__ unsigned val_lds[SLOT];
    __shared__ ushort rank_lds[SLOT];
    int tid = threadIdx.x;
    int b = blockIdx.x;

    // bucket-base scan (every block does the 196-wide scan itself)
    int c = (tid < NB) ? min(bucketCursor[tid], SLOT) : 0;
    bscan[tid] = c;
    __syncthreads();
    #pragma unroll
    for (int off = 1; off < 256; off <<= 1) {
        int add = (tid >= off) ? bscan[tid - off] : 0;
        __syncthreads();
        bscan[tid] += add;
        __syncthreads();
    }
    int myBase = b ? bscan[b - 1] : 0;
    int count  = bscan[b] - myBase;
    __syncthreads();

    cw[tid] = 0;
    __syncthreads();

    // pass 1: count per local dst, stage values + ranks
    const unsigned* pb = pairs + (size_t)b * SLOT;
    for (int p = tid; p < count; p += 256) {
        unsigned v = pb[p];
        int dl = (v >> 16) & 255;
        int r = atomicAdd(&cw[dl], 1);
        val_lds[p] = v;
        rank_lds[p] = (ushort)r;
    }
    __syncthreads();
    int cnode = cw[tid];
    bscan[tid] = cnode;           // reuse for node scan
    __syncthreads();
    #pragma unroll
    for (int off = 1; off < 256; off <<= 1) {
        int add = (tid >= off) ? bscan[tid - off] : 0;
        __syncthreads();
        bscan[tid] += add;
        __syncthreads();
    }
    int preEx = bscan[tid] - cnode;
    pre2[tid] = preEx;
    int nodeBase = b << 8;
    if (nodeBase + tid < NN) rowptr[nodeBase + tid] = myBase + preEx;
    if (b == NB - 1 && tid == 0) rowptr[NN] = myBase + count;
    __syncthreads();

    // pass 2: scatter col within bucket region (single-XCD locality)
    for (int p = tid; p < count; p += 256) {
        unsigned v = val_lds[p];
        int dl = (v >> 16) & 255;
        int pos = myBase + pre2[dl] + (int)rank_lds[p];
        colS[pos] = (ushort)(v & 0xFFFF);
    }
}

// ---------------------------------------------------------------------------
// Fused layer (r6 structure). Gather: wave = 4 groups of 16 lanes; each
// group owns edge parity (e % 4), ushort8 = 16B/lane covers a 256B row;
// 2-deep unroll => 8 rows in flight per wave. rowptr preloaded via shfl.
// featB row layout (bytes): agg = [0,256), self = [256,512), XOR-swizzled.
// ---------------------------------------------------------------------------
template <int DO_HEAD>
__global__ __launch_bounds__(256) void sage_fused_kernel(
    const ushort* __restrict__ featG,     // bf16 [N][128]
    const int* __restrict__ rowptr, const ushort* __restrict__ colS,
    const ushort* __restrict__ WtB,       // bf16 [128 j][256 k]
    const float* __restrict__ bl,
    const float* __restrict__ g, const float* __restrict__ beta,
    const float* __restrict__ Wh, const float* __restrict__ bh,
    void* __restrict__ outp)
{
    __shared__ __align__(16) char smem[32 * OTS * 4];   // 16.9 KB
    __shared__ float mu_s[32], ri_s[32];
    ushort* featB = (ushort*)smem;            // [32][256] bf16, swizzled
    float*  oT    = (float*)smem;             // overlays featB after MFMA
    #define OT(n, k) oT[(n) * OTS + (k)]

    int tid = threadIdx.x;
    int base = blockIdx.x * 32;
    int lane = tid & 63, w = tid >> 6;

    // ---- self-feature part: featB bytes [256,512), ushort8 ----
    #pragma unroll
    for (int i = 0; i < 2; i++) {
        int idx = tid + i * 256;
        int n = idx >> 4, c = idx & 15;
        int node = base + n;
        short8v xv = {};
        if (node < NN) xv = *(const short8v*)(featG + (size_t)node * DIM + c * 8);
        int kb = (256 + c * 16) ^ ((n & 7) << 4);   // byte offset
        *(short8v*)(featB + n * KK + (kb >> 1)) = xv;
    }

    // ---- gather-mean: featB bytes [0,256) ----
    {
        int lane16 = lane & 15, grp = lane >> 4;
        int rp = 0;
        {
            int ridx = base + w * 8 + lane;
            if (lane < 9) rp = rowptr[min(ridx, NN)];
        }
        for (int i = 0; i < 8; i++) {
            int n = w * 8 + i;
            int beg = __shfl(rp, i, 64);
            int end = __shfl(rp, i + 1, 64);
            int deg = end - beg;
            float a0[8], a1[8];
            #pragma unroll
            for (int c = 0; c < 8; c++) { a0[c] = 0.f; a1[c] = 0.f; }
            int e = beg + grp;
            for (; e + 4 < end; e += 8) {
                int s0 = colS[e], s1 = colS[e + 4];
                short8v v0 = *(const short8v*)(featG + (size_t)s0 * DIM + lane16 * 8);
                short8v v1 = *(const short8v*)(featG + (size_t)s1 * DIM + lane16 * 8);
                #pragma unroll
                for (int c = 0; c < 8; c++) {
                    a0[c] += bf2f((unsigned short)v0[c]);
                    a1[c] += bf2f((unsigned short)v1[c]);
                }
            }
            if (e < end) {
                int s0 = colS[e];
                short8v v0 = *(const short8v*)(featG + (size_t)s0 * DIM + lane16 * 8);
                #pragma unroll
                for (int c = 0; c < 8; c++) a0[c] += bf2f((unsigned short)v0[c]);
            }
            #pragma unroll
            for (int c = 0; c < 8; c++) {
                a0[c] += a1[c];
                a0[c] += __shfl_xor(a0[c], 16, 64);
                a0[c] += __shfl_xor(a0[c], 32, 64);
            }
            if (grp == 0) {
                float di = 1.0f / fmaxf((float)deg, 1.0f);
                short8v o;
                #pragma unroll
                for (int c = 0; c < 8; c++) o[c] = (short)f2bf(a0[c] * di);
                int kb = (lane16 * 16) ^ ((n & 7) << 4);
                *(short8v*)(featB + n * KK + (kb >> 1)) = o;
            }
        }
    }
    __syncthreads();

    // ---- MFMA: C[32][128] = featB[32][256] x W[256][128] ----
    int l15 = lane & 15, q = lane >> 4;
    f32x4v acc00 = {}, acc01 = {}, acc10 = {}, acc11 = {};
    const ushort* wbase = WtB + (size_t)(w * 32) * KK;
    int n0 = l15, n1 = 16 + l15;
    int sw = (l15 & 7) << 4;
    #pragma unroll
    for (int ks = 0; ks < 8; ks++) {
        int kbA = ks * 64 + q * 16;                  // byte offset
        short8v a0 = *(const short8v*)(featB + n0 * KK + (((kbA) ^ sw) >> 1));
        short8v a1 = *(const short8v*)(featB + n1 * KK + (((kbA) ^ sw) >> 1));
        int koff = ks * 32 + q * 8;
        short8v b0 = *(const short8v*)(wbase + (size_t)l15 * KK + koff);
        short8v b1 = *(const short8v*)(wbase + (size_t)(16 + l15) * KK + koff);
        acc00 = __builtin_amdgcn_mfma_f32_16x16x32_bf16(a0, b0, acc00, 0, 0, 0);
        acc01 = __builtin_amdgcn_mfma_f32_16x16x32_bf16(a0, b1, acc01, 0, 0, 0);
        acc10 = __builtin_amdgcn_mfma_f32_16x16x32_bf16(a1, b0, acc10, 0, 0, 0);
        acc11 = __builtin_amdgcn_mfma_f32_16x16x32_bf16(a1, b1, acc11, 0, 0, 0);
    }
    __syncthreads();   // all featB reads done before oT overlays it

    // D layout: col = lane&15, row = (lane>>4)*4 + r
    {
        int c0 = w * 32 + l15, c1 = c0 + 16;
        float bl0v = bl[c0], bl1v = bl[c1];
        #pragma unroll
        for (int r = 0; r < 4; r++) {
            int r0 = q * 4 + r, r1 = 16 + q * 4 + r;
            OT(r0, c0) = acc00[r] + bl0v;
            OT(r0, c1) = acc01[r] + bl1v;
            OT(r1, c0) = acc10[r] + bl0v;
            OT(r1, c1) = acc11[r] + bl1v;
        }
    }
    __syncthreads();

    // ---- LayerNorm stats (f32): 8 threads per node ----
    {
        int n = tid >> 3, l = tid & 7;
        float s = 0.f, s2 = 0.f;
        #pragma unroll
        for (int kk = 0; kk < 16; kk++) {
            float v = OT(n, l * 16 + kk);
            s += v; s2 += v * v;
        }
        #pragma unroll
        for (int off = 4; off; off >>= 1) {
            s  += __shfl_down(s, off, 8);
            s2 += __shfl_down(s2, off, 8);
        }
        if (l == 0) {
            float mu = s * (1.0f / DIM);
            float var = s2 * (1.0f / DIM) - mu * mu;
            mu_s[n] = mu;
            ri_s[n] = rsqrtf(fmaxf(var, 0.f) + EPSV);
        }
    }
    __syncthreads();

    if (!DO_HEAD) {
        ushort* hout = (ushort*)outp;
        #pragma unroll
        for (int i = 0; i < 16; i++) {
            int idx = tid + i * 256;
            int n = idx >> 7, k = idx & 127;
            int node = base + n;
            if (node < NN) {
                float v = (OT(n, k) - mu_s[n]) * ri_s[n] * g[k] + beta[k];
                hout[(size_t)node * DIM + k] = f2bf(fmaxf(v, 0.f));
            }
        }
    } else {
        float* fout = (float*)outp;
        float vals[16];
        #pragma unroll
        for (int i = 0; i < 16; i++) {
            int idx = tid + i * 256;
            int n = idx >> 7, k = idx & 127;
            float v = (OT(n, k) - mu_s[n]) * ri_s[n] * g[k] + beta[k];
            vals[i] = fmaxf(v, 0.f);
        }
        __syncthreads();
        #pragma unroll
        for (int i = 0; i < 16; i++) {
            int idx = tid + i * 256;
            int n = idx >> 7, k = idx & 127;
            OT(n, k) = vals[i];
        }
        __syncthreads();
        if (tid < 128) {
            int n = tid >> 2, o = tid & 3;
            int node = base + n;
            if (node < NN) {
                float s = bh[o];
                for (int k = 0; k < DIM; k++) s += OT(n, k) * Wh[k * OUTD + o];
                fout[(size_t)node * OUTD + o] = s;
            }
        }
    }
    #undef OT
}

extern "C" void kernel_launch(void* const* d_in, const int* in_sizes, int n_in,
                              void* d_out, int out_size, void* d_ws, size_t ws_size,
                              hipStream_t stream)
{
    const float* x    = (const float*)d_in[0];
    const int*   ei   = (const int*)d_in[1];   // [2, E] int32
    const float* Wl0  = (const float*)d_in[2];
    const float* bl0  = (const float*)d_in[3];
    const float* Wr0  = (const float*)d_in[4];
    const float* Wl1  = (const float*)d_in[5];
    const float* bl1  = (const float*)d_in[6];
    const float* Wr1  = (const float*)d_in[7];
    const float* g0   = (const float*)d_in[8];
    const float* be0  = (const float*)d_in[9];
    const float* g1   = (const float*)d_in[10];
    const float* be1  = (const float*)d_in[11];
    const float* Wh   = (const float*)d_in[12];
    const float* bh   = (const float*)d_in[13];
    float* out = (float*)d_out;

    const int* srcI = ei;
    const int* dstI = ei + EE;

    // ws layout (16B-aligned): xb | h | Wt0 | Wt1 | rowptr | bucketCursor | pairs | colS
    char* p = (char*)d_ws;
    ushort*   xb     = (ushort*)p;    p += (size_t)NN * DIM * 2;        // 12.8 MB
    ushort*   h      = (ushort*)p;    p += (size_t)NN * DIM * 2;        // 12.8 MB
    ushort*   Wt0    = (ushort*)p;    p += DIM * KK * 2;                // 64 KB
    ushort*   Wt1    = (ushort*)p;    p += DIM * KK * 2;                // 64 KB
    int*      rowptr = (int*)p;       p += 50016 * 4;                   // N+1, padded
    int*      bucketCursor = (int*)p; p += 256 * 4;
    unsigned* pairs  = (unsigned*)p;  p += (size_t)NB * SLOT * 4;       // 6.4 MB
    ushort*   colS   = (ushort*)p;    p += (size_t)EE * 2;              // 1.6 MB

    prep_kernel<<<XB_BLK + W_BLK + 1, 256, 0, stream>>>(
        x, xb, Wl0, Wr0, Wl1, Wr1, Wt0, Wt1, bucketCursor);
    passA_kernel<<<NA, 256, 0, stream>>>(srcI, dstI, bucketCursor, pairs);
    passB_kernel<<<NB, 256, 0, stream>>>(bucketCursor, pairs, rowptr, colS);

    const int blocks = (NN + 31) / 32;
    sage_fused_kernel<0><<<blocks, 256, 0, stream>>>(
        xb, rowptr, colS, Wt0, bl0, g0, be0, nullptr, nullptr, (void*)h);
    sage_fused_kernel<1><<<blocks, 256, 0, stream>>>(
        h, rowptr, colS, Wt1, bl1, g1, be1, Wh, bh, (void*)out);
}